// Round 19
// baseline (2805.435 us; speedup 1.0000x reference)
//
#include <hip/hip_runtime.h>
#include <hip/hip_bf16.h>

// SNN, 5 layers, T=100, B=512.  R19 = R17 with 1024-THREAD pipeline blocks
// (16 waves -> 4 waves/SIMD, was 2): hidden wave row-tile halves to 16 rows,
// accumulators halve (acc 64 VGPR) to fit the 128-VGPR/4-wave boundary.
// B-frag reg-prefetch dropped (neutral in R14/R17, saves 32 VGPR); bit-word
// prefetch + ck desync + setprio kept. Same per-output math -> absmax 0.

#define NB 512
#define NH 1024
#define NI 512
#define NO 35
#define TT 100
#define NT 8
#define BITFRAME 16384   // u32 words per 512x1024 bit frame (64KB)

typedef __bf16 bf16x8 __attribute__((ext_vector_type(8)));
typedef float f32x4 __attribute__((ext_vector_type(4)));
typedef int   i32x4 __attribute__((ext_vector_type(4)));

__device__ __forceinline__ size_t tiled_off(int row, int k, int KT) {
    return ((size_t)((row >> 4) * KT + (k >> 5)) * 64
            + (row & 15) + (((k >> 3) & 3) << 4)) * 8 + (k & 7);
}

__device__ __forceinline__ void leaky_upd(float zin, float mprev, float be, float th,
                                          float& mnew, float& spk) {
    float rs = (mprev - th > 0.0f) ? th : 0.0f;
    float bc = fminf(fmaxf(be, 0.0f), 1.0f);
    mnew = bc * mprev + zin - rs;
    spk  = (mnew - th > 0.0f) ? 1.0f : 0.0f;
}

// ---------------- ws layout (bytes) ----------------
#define WS_MEM123   0u           // 6,291,456
#define WS_MEM0     6291456u     // 2,097,152 (tiled-linear fp32)
#define WS_MEMO     8388608u     // 98,304
#define WS_FLAGS    8486912u     // 1,024
#define WS_GEN      8487936u     // 256
#define WS_RING0    8488192u     // 16 frames = 1,048,576 each
#define WS_RING1    9536768u
#define WS_RING2    10585344u
#define WS_RING3    11633920u
#define WS_W8       12682496u    // 12,582,912 (3 layers x 4 planes x 1MB i8)
#define WS_WIT      25265408u    // 3,145,728 (W_in bf16 3 planes, KT=16)
#define WS_WOT      28411136u    // 294,912   (W_out bf16, 48 rows, 3 planes)
#define WS_Z0       28706048u    // Tc * 2,097,152
#define STEP_BYTES  2097152u

// ---------------- weight splits ----------------
__global__ __launch_bounds__(256)
void split_weights_i8(const float* __restrict__ W_h, signed char* __restrict__ W8) {
    const int id = blockIdx.x * 256 + threadIdx.x;        // 3*1024*64
    const int layer = id >> 16;
    const int rem = id & 65535;
    const int n = rem >> 6;
    const int k0 = (rem & 63) << 4;                        // 16 k per thread
    const float* src = W_h + ((size_t)layer * NH + n) * NH + k0;
    const int kq = k0 >> 4;
    const int ck = kq >> 2;
    const int lane = (n & 15) | ((kq & 3) << 4);
    signed char* dstL = W8 + (size_t)layer * 4 * NH * NH;
    const size_t gb = ((size_t)(n >> 4) * 16 + ck) * 1024 + lane * 16;

    signed char q1[16], q2[16], q3[16], q4[16];
    #pragma unroll
    for (int j = 0; j < 16; ++j) {
        float w = src[j];
        float f1 = rintf(w * 0x1p11f);   float r1 = w  - f1 * 0x1p-11f;
        float f2 = rintf(r1 * 0x1p18f);  float r2 = r1 - f2 * 0x1p-18f;
        float f3 = rintf(r2 * 0x1p25f);  float r3 = r2 - f3 * 0x1p-25f;
        float f4 = rintf(r3 * 0x1p32f);
        q1[j] = (signed char)(int)f1; q2[j] = (signed char)(int)f2;
        q3[j] = (signed char)(int)f3; q4[j] = (signed char)(int)f4;
    }
    #pragma unroll
    for (int j = 0; j < 16; ++j) {
        dstL[(size_t)0 * 64 * 16384 + gb + j] = q1[j];
        dstL[(size_t)1 * 64 * 16384 + gb + j] = q2[j];
        dstL[(size_t)2 * 64 * 16384 + gb + j] = q3[j];
        dstL[(size_t)3 * 64 * 16384 + gb + j] = q4[j];
    }
}

__global__ __launch_bounds__(256)
void split_win(const float* __restrict__ W_in, __bf16* __restrict__ Wi_t) {
    const int id = blockIdx.x * 256 + threadIdx.x;
    const int n = id >> 6;
    const int k0 = (id & 63) << 3;
    const float* src = W_in + (size_t)n * NI + k0;
    const size_t PS = (size_t)NH * NI;
    const size_t off = tiled_off(n, k0, 16);
    bf16x8 p1, p2, p3;
    #pragma unroll
    for (int j = 0; j < 8; ++j) {
        float w = src[j];
        __bf16 a = (__bf16)w;  float r1 = w - (float)a;
        __bf16 b = (__bf16)r1; float r2 = r1 - (float)b;
        __bf16 c = (__bf16)r2;
        p1[j] = a; p2[j] = b; p3[j] = c;
    }
    *reinterpret_cast<bf16x8*>(Wi_t + 0 * PS + off) = p1;
    *reinterpret_cast<bf16x8*>(Wi_t + 1 * PS + off) = p2;
    *reinterpret_cast<bf16x8*>(Wi_t + 2 * PS + off) = p3;
}

__global__ __launch_bounds__(256)
void split_wout(const float* __restrict__ W_out, __bf16* __restrict__ Wo_t) {
    const int id = blockIdx.x * 256 + threadIdx.x;
    if (id >= 48 * 128) return;
    const int o = id >> 7;
    const int k0 = (id & 127) << 3;
    const size_t PS = (size_t)48 * NH;
    const size_t off = tiled_off(o, k0, 32);
    bf16x8 p1 = {}, p2 = {}, p3 = {};
    if (o < NO) {
        const float* src = W_out + (size_t)o * NH + k0;
        #pragma unroll
        for (int j = 0; j < 8; ++j) {
            float w = src[j];
            __bf16 a = (__bf16)w;  float r1 = w - (float)a;
            __bf16 b = (__bf16)r1; float r2 = r1 - (float)b;
            __bf16 c = (__bf16)r2;
            p1[j] = a; p2[j] = b; p3[j] = c;
        }
    }
    *reinterpret_cast<bf16x8*>(Wo_t + 0 * PS + off) = p1;
    *reinterpret_cast<bf16x8*>(Wo_t + 1 * PS + off) = p2;
    *reinterpret_cast<bf16x8*>(Wo_t + 2 * PS + off) = p3;
}

// ---------------- Z0 = data @ W_in^T + b_in ---------------------------------
__global__ __launch_bounds__(256)
void z0_gemm(const float* __restrict__ X,
             const __bf16* __restrict__ Wi_t,
             const float* __restrict__ bias,
             float* __restrict__ Z0)
{
    const int tid = threadIdx.x;
    const int lane = tid & 63;
    const int w = tid >> 6;
    const int wm = w >> 1, wn = w & 1;
    const int m_base = blockIdx.y * 64 + wm * 32;
    const int n_base = blockIdx.x * 128 + wn * 64;
    const size_t PS = (size_t)NH * NI;

    f32x4 acc[2][4] = {};
    const float* asrc[2];
    #pragma unroll
    for (int mt = 0; mt < 2; ++mt)
        asrc[mt] = X + (size_t)(m_base + mt * 16 + (lane & 15)) * NI + ((lane >> 4) << 3);

    float4 c0[2], c1[2];
    #pragma unroll
    for (int mt = 0; mt < 2; ++mt) {
        c0[mt] = *reinterpret_cast<const float4*>(asrc[mt]);
        c1[mt] = *reinterpret_cast<const float4*>(asrc[mt] + 4);
    }

    for (int kt = 0; kt < 16; ++kt) {
        float4 n0[2], n1[2];
        if (kt < 15) {
            #pragma unroll
            for (int mt = 0; mt < 2; ++mt) {
                n0[mt] = *reinterpret_cast<const float4*>(asrc[mt] + (kt + 1) * 32);
                n1[mt] = *reinterpret_cast<const float4*>(asrc[mt] + (kt + 1) * 32 + 4);
            }
        }
        bf16x8 a1[2], a2[2], a3[2];
        #pragma unroll
        for (int mt = 0; mt < 2; ++mt) {
            float xv[8] = {c0[mt].x, c0[mt].y, c0[mt].z, c0[mt].w,
                           c1[mt].x, c1[mt].y, c1[mt].z, c1[mt].w};
            #pragma unroll
            for (int j = 0; j < 8; ++j) {
                float x = xv[j];
                __bf16 h1 = (__bf16)x;  float r1 = x - (float)h1;
                __bf16 h2 = (__bf16)r1; float r2 = r1 - (float)h2;
                __bf16 h3 = (__bf16)r2;
                a1[mt][j] = h1; a2[mt][j] = h2; a3[mt][j] = h3;
            }
        }
        #pragma unroll
        for (int nt = 0; nt < 4; ++nt) {
            const size_t bo = ((size_t)(((n_base >> 4) + nt) * 16 + kt) * 64 + lane) * 8;
            bf16x8 b1 = *reinterpret_cast<const bf16x8*>(Wi_t + bo);
            bf16x8 b2 = *reinterpret_cast<const bf16x8*>(Wi_t + PS + bo);
            bf16x8 b3 = *reinterpret_cast<const bf16x8*>(Wi_t + 2 * PS + bo);
            #pragma unroll
            for (int mt = 0; mt < 2; ++mt) {
                f32x4 A = acc[mt][nt];
                A = __builtin_amdgcn_mfma_f32_16x16x32_bf16(a1[mt], b1, A, 0, 0, 0);
                A = __builtin_amdgcn_mfma_f32_16x16x32_bf16(a1[mt], b2, A, 0, 0, 0);
                A = __builtin_amdgcn_mfma_f32_16x16x32_bf16(a2[mt], b1, A, 0, 0, 0);
                A = __builtin_amdgcn_mfma_f32_16x16x32_bf16(a2[mt], b2, A, 0, 0, 0);
                A = __builtin_amdgcn_mfma_f32_16x16x32_bf16(a1[mt], b3, A, 0, 0, 0);
                A = __builtin_amdgcn_mfma_f32_16x16x32_bf16(a3[mt], b1, A, 0, 0, 0);
                acc[mt][nt] = A;
            }
        }
        if (kt < 15) {
            #pragma unroll
            for (int mt = 0; mt < 2; ++mt) { c0[mt] = n0[mt]; c1[mt] = n1[mt]; }
        }
    }

    const int c = lane & 15;
    const int r0 = (lane >> 4) * 4;
    #pragma unroll
    for (int nt = 0; nt < 4; ++nt) {
        const int n = n_base + nt * 16 + c;
        const float bi = bias[n];
        #pragma unroll
        for (int mt = 0; mt < 2; ++mt) {
            #pragma unroll
            for (int r = 0; r < 4; ++r) {
                const int m = m_base + mt * 16 + r0 + r;
                const int tl = m >> 9, b = m & 511;
                Z0[(size_t)tl * (NB * NH) + tiled_off(b, n, 32)] = acc[mt][nt][r] + bi;
            }
        }
    }
}

// ---------------- grid barrier (256 blocks) ----------------------------------
__device__ __forceinline__ void gridbar(int* flags, int* gen, int target) {
    __syncthreads();
    if (threadIdx.x == 0) {
        __builtin_amdgcn_fence(__ATOMIC_RELEASE, "agent");
        __hip_atomic_store(&flags[blockIdx.x], target, __ATOMIC_RELAXED, __HIP_MEMORY_SCOPE_AGENT);
    }
    if (blockIdx.x == 0) {
        if (threadIdx.x < 64) {
            const int l = threadIdx.x;
            for (;;) {
                int v0 = __hip_atomic_load(&flags[l],       __ATOMIC_RELAXED, __HIP_MEMORY_SCOPE_AGENT);
                int v1 = __hip_atomic_load(&flags[l + 64],  __ATOMIC_RELAXED, __HIP_MEMORY_SCOPE_AGENT);
                int v2 = __hip_atomic_load(&flags[l + 128], __ATOMIC_RELAXED, __HIP_MEMORY_SCOPE_AGENT);
                int v3 = __hip_atomic_load(&flags[l + 192], __ATOMIC_RELAXED, __HIP_MEMORY_SCOPE_AGENT);
                int mn = min(min(v0, v1), min(v2, v3));
                if (__all(mn >= target)) break;
                __builtin_amdgcn_s_sleep(1);
            }
        }
        __syncthreads();
        if (threadIdx.x == 0) {
            __builtin_amdgcn_fence(__ATOMIC_ACQ_REL, "agent");
            __hip_atomic_store(gen, target, __ATOMIC_RELAXED, __HIP_MEMORY_SCOPE_AGENT);
        }
    } else if (threadIdx.x == 0) {
        while (__hip_atomic_load(gen, __ATOMIC_RELAXED, __HIP_MEMORY_SCOPE_AGENT) < target)
            __builtin_amdgcn_s_sleep(2);
    }
    __syncthreads();
    __builtin_amdgcn_fence(__ATOMIC_ACQUIRE, "agent");
}

// ---------------- hidden NS-step body (i8 4-plane, 16-row wave tile) ---------
template<int NS>
__device__ __forceinline__ void hidden_run_i8(
    const unsigned int* const* Xp, unsigned short* const* Yp,
    const signed char* Wl, int cs, int mt16, int lane, int ckoff,
    float (&memr)[2][4], const float (&bi)[2], const float (&be)[2],
    const float (&th)[2])
{
    const int row  = lane & 15;
    const int lg   = lane >> 4;
    const int wsel = lg >> 1;
    const int hsel = (lg & 1) * 16;

    i32x4 acc[NS][2][4] = {};       // [q][nt][plane]

    unsigned int bw[NS];
    #pragma unroll
    for (int q = 0; q < NS; ++q)
        bw[q] = Xp[q][(mt16 * 32 + ckoff * 2 + wsel) * 16 + row];

    for (int ckk = 0; ckk < 16; ++ckk) {
        const int ck  = (ckk + ckoff) & 15;
        const int ckn = (ck + 1) & 15;
        unsigned int nb[NS];
        if (ckk < 15) {
            #pragma unroll
            for (int q = 0; q < NS; ++q)
                nb[q] = Xp[q][(mt16 * 32 + ckn * 2 + wsel) * 16 + row];
        }
        i32x4 bf[8];
        #pragma unroll
        for (int pn = 0; pn < 8; ++pn)
            bf[pn] = *reinterpret_cast<const i32x4*>(Wl + pn * 16384 + ck * 1024 + lane * 16);

        __builtin_amdgcn_s_setprio(1);
        #pragma unroll
        for (int q = 0; q < NS; ++q) {
            unsigned int half = (bw[q] >> hsel) & 0xFFFFu;
            union { unsigned int u[4]; i32x4 v; } a;
            a.u[0] = (((half      ) & 0xFu) * 0x204081u) & 0x01010101u;
            a.u[1] = (((half >>  4) & 0xFu) * 0x204081u) & 0x01010101u;
            a.u[2] = (((half >>  8) & 0xFu) * 0x204081u) & 0x01010101u;
            a.u[3] = (((half >> 12) & 0xFu) * 0x204081u) & 0x01010101u;
            #pragma unroll
            for (int nt = 0; nt < 2; ++nt)
                #pragma unroll
                for (int p = 0; p < 4; ++p)
                    acc[q][nt][p] = __builtin_amdgcn_mfma_i32_16x16x64_i8(
                        a.v, bf[p * 2 + nt], acc[q][nt][p], 0, 0, 0);
        }
        __builtin_amdgcn_s_setprio(0);

        if (ckk < 15) {
            #pragma unroll
            for (int q = 0; q < NS; ++q) bw[q] = nb[q];
        }
    }

    #pragma unroll
    for (int q = 0; q < NS; ++q) {
        #pragma unroll
        for (int nt = 0; nt < 2; ++nt) {
            #pragma unroll
            for (int r = 0; r < 4; ++r) {
                float z = (float)acc[q][nt][3][r] * 0x1p-32f
                        + (float)acc[q][nt][2][r] * 0x1p-25f;
                z += (float)acc[q][nt][1][r] * 0x1p-18f;
                z += (float)acc[q][nt][0][r] * 0x1p-11f;
                float mn, sp;
                leaky_upd(z + bi[nt], memr[nt][r], be[nt], th[nt], mn, sp);
                memr[nt][r] = mn;
                unsigned long long bal = __ballot(sp != 0.0f);
                if ((lane & 15) == 0) {
                    const int rr = (lane >> 4) * 4 + r;
                    Yp[q][((mt16 * 32 + cs) * 16 + rr) * 2 + nt] =
                        (unsigned short)((bal >> ((lane >> 4) * 16)) & 0xFFFFu);
                }
            }
        }
    }
}

// ---------------- the 5-stage persistent pipeline (1024 threads) -------------
__global__ __launch_bounds__(1024, 1)
void snn_pipe(const float* __restrict__ Z0,
              const signed char* __restrict__ W8,
              const __bf16* __restrict__ Wo_t,
              const float* __restrict__ b_h,
              const float* __restrict__ b_out,
              const float* __restrict__ beta_h,
              const float* __restrict__ thr_h,
              const float* __restrict__ beta_o,
              const float* __restrict__ thr_o,
              float* __restrict__ mem123,
              float* __restrict__ mem0_g,
              float* __restrict__ memo_g,
              unsigned int* __restrict__ ring0, unsigned int* __restrict__ ring1,
              unsigned int* __restrict__ ring2, unsigned int* __restrict__ ring3,
              float* __restrict__ out,
              int* __restrict__ flags, int* __restrict__ gen,
              int t0, int tc)
{
    __shared__ signed char Wl[8 * 16 * 1024];    // 128 KB i8 weights
    __shared__ unsigned long long lut[16];       // for out stage

    const int blk  = blockIdx.x;
    const int tid  = threadIdx.x;
    const int lane = tid & 63;
    const int w    = tid >> 6;                   // 0..15

    if (tid < 16) {
        unsigned int lo = ((tid & 1) ? 0x3F80u : 0u) | ((tid & 2) ? 0x3F800000u : 0u);
        unsigned int hi = ((tid & 4) ? 0x3F80u : 0u) | ((tid & 8) ? 0x3F800000u : 0u);
        lut[tid] = ((unsigned long long)hi << 32) | lo;
    }

    const int G = (tc + NT - 1) / NT;

    if (blk < 192) {
        // ================= hidden layers (i8), 16 waves x 16-row tiles =======
        const int ell = blk >> 6;
        const int cs  = (blk & 63) >> 1;
        const int rh  = blk & 1;
        const int mt16 = rh * 16 + w;            // this wave's 16-row tile
        const int ckoff = ((w >> 2) & 3) * 4;    // desync the 4 waves per SIMD
        {
            const signed char* Wsrc = W8 + (size_t)ell * 4 * NH * NH;
            for (int idx = tid; idx < 8 * 1024; idx += 1024) {
                const int pn = idx >> 10, off = idx & 1023;
                const int p = pn >> 1, nt = pn & 1;
                *reinterpret_cast<int4*>(Wl + pn * 16384 + off * 16) =
                    *reinterpret_cast<const int4*>(
                        Wsrc + (size_t)(p * 64 + cs * 2 + nt) * 16384 + off * 16);
            }
        }

        const int c = lane & 15;
        const int r0v = (lane >> 4) * 4;
        float* memg = mem123 + (size_t)ell * (NB * NH);
        float bi[2], be[2], th[2];
        #pragma unroll
        for (int nt = 0; nt < 2; ++nt) {
            const int n = cs * 32 + nt * 16 + c;
            bi[nt] = b_h[ell * NH + n];
            be[nt] = beta_h[(ell + 1) * NH + n];
            th[nt] = thr_h[(ell + 1) * NH + n];
        }
        float memr[2][4];
        #pragma unroll
        for (int nt = 0; nt < 2; ++nt)
            #pragma unroll
            for (int r = 0; r < 4; ++r)
                memr[nt][r] = memg[(size_t)(mt16 * 16 + r0v + r) * NH
                                   + cs * 32 + nt * 16 + c];

        const unsigned int* rin = (ell == 0) ? ring0 : (ell == 1) ? ring1 : ring2;
        unsigned int* rout      = (ell == 0) ? ring1 : (ell == 1) ? ring2 : ring3;

        __syncthreads();

        for (int p = 0; p < G + 4; ++p) {
            const int g = p - 1 - ell;
            if (g >= 0 && g < G) {
                const int sbase = g * NT;
                const int send  = (sbase + NT < tc) ? sbase + NT : tc;
                const int slot0 = (g & 1) * NT;
                int s = sbase;
                while (s < send) {
                    const int base = slot0 + (s - sbase);
                    const unsigned int* Xp[2];
                    unsigned short* Yp[2];
                    if (send - s >= 2) {
                        #pragma unroll
                        for (int q = 0; q < 2; ++q) {
                            Xp[q] = rin + (size_t)(base + q) * BITFRAME;
                            Yp[q] = (unsigned short*)(rout + (size_t)(base + q) * BITFRAME);
                        }
                        hidden_run_i8<2>(Xp, Yp, Wl, cs, mt16, lane, ckoff, memr, bi, be, th);
                        s += 2;
                    } else {
                        Xp[0] = rin + (size_t)base * BITFRAME;
                        Yp[0] = (unsigned short*)(rout + (size_t)base * BITFRAME);
                        hidden_run_i8<1>(Xp, Yp, Wl, cs, mt16, lane, ckoff, memr, bi, be, th);
                        s += 1;
                    }
                }
            }
            gridbar(flags, gen, p + 1);
        }

        #pragma unroll
        for (int nt = 0; nt < 2; ++nt)
            #pragma unroll
            for (int r = 0; r < 4; ++r)
                memg[(size_t)(mt16 * 16 + r0v + r) * NH
                     + cs * 32 + nt * 16 + c] = memr[nt][r];
    } else if (blk < 224) {
        // ================= output layer (bf16 LUT), waves 0..2 ===============
        const bool outw = (w < 3);
        const int omt = blk - 192;
        const int ont = w;
        const int c = lane & 15, r0v = (lane >> 4) * 4;
        const int row = lane & 15, sh2 = (lane >> 4) * 8;
        const int oo = ont * 16 + c;
        const size_t OPS = (size_t)48 * NH;
        float mo[4] = {0.f, 0.f, 0.f, 0.f};
        float obi = 0.f, obe = 0.f, oth = 1.f;
        if (outw && oo < NO) {
            obi = b_out[oo]; obe = beta_o[oo]; oth = thr_o[oo];
            #pragma unroll
            for (int r = 0; r < 4; ++r) mo[r] = memo_g[(omt * 16 + r0v + r) * NO + oo];
        }
        __syncthreads();

        for (int p = 0; p < G + 4; ++p) {
            if (outw) {
                const int go = p - 4;
                if (go >= 0 && go < G) {
                    const int sbase = go * NT;
                    const int send  = (sbase + NT < tc) ? sbase + NT : tc;
                    const int slot0 = (go & 1) * NT;
                    for (int s = sbase; s < send; ++s) {
                        const unsigned int* Xw =
                            ring3 + (size_t)(slot0 + s - sbase) * BITFRAME;
                        f32x4 acc = {};
                        for (int kt = 0; kt < 32; ++kt) {
                            unsigned int by = (Xw[(omt * 32 + kt) * 16 + row] >> sh2) & 0xffu;
                            union { unsigned long long u[2]; bf16x8 v; } a;
                            a.u[0] = lut[by & 15u];
                            a.u[1] = lut[by >> 4];
                            const size_t bo = ((size_t)(ont * 32 + kt) * 64 + lane) * 8;
                            bf16x8 q1 = *reinterpret_cast<const bf16x8*>(Wo_t + bo);
                            bf16x8 q2 = *reinterpret_cast<const bf16x8*>(Wo_t + OPS + bo);
                            bf16x8 q3 = *reinterpret_cast<const bf16x8*>(Wo_t + 2 * OPS + bo);
                            acc = __builtin_amdgcn_mfma_f32_16x16x32_bf16(a.v, q1, acc, 0, 0, 0);
                            acc = __builtin_amdgcn_mfma_f32_16x16x32_bf16(a.v, q2, acc, 0, 0, 0);
                            acc = __builtin_amdgcn_mfma_f32_16x16x32_bf16(a.v, q3, acc, 0, 0, 0);
                        }
                        if (oo < NO) {
                            #pragma unroll
                            for (int r = 0; r < 4; ++r) {
                                float mn, sp;
                                leaky_upd(acc[r] + obi, mo[r], obe, oth, mn, sp);
                                mo[r] = mn;
                                out[((size_t)(t0 + s) * NB + omt * 16 + r0v + r) * NO + oo] = sp;
                            }
                        }
                    }
                }
            }
            gridbar(flags, gen, p + 1);
        }

        if (outw && oo < NO) {
            #pragma unroll
            for (int r = 0; r < 4; ++r) memo_g[(omt * 16 + r0v + r) * NO + oo] = mo[r];
        }
    } else {
        // ================= leaky0: first 512 threads do the work =============
        const bool act = (tid < 512);
        const int wi   = (blk - 224) * 512 + tid;     // valid when act
        const int mtb  = wi >> 9;
        const int ktb  = (wi >> 4) & 31;
        const int i0   = (mtb * 32 + ktb) * 512 + (wi & 15) * 8;

        float m0[32], be0[32], th0[32];
        if (act) {
            #pragma unroll
            for (int byt = 0; byt < 4; ++byt)
                #pragma unroll
                for (int j = 0; j < 8; ++j) {
                    m0[byt * 8 + j]  = mem0_g[i0 + byt * 128 + j];
                    be0[byt * 8 + j] = beta_h[ktb * 32 + byt * 8 + j];
                    th0[byt * 8 + j] = thr_h[ktb * 32 + byt * 8 + j];
                }
        }
        __syncthreads();

        for (int p = 0; p < G + 4; ++p) {
            if (act && p < G) {
                const int sbase = p * NT;
                const int send  = (sbase + NT < tc) ? sbase + NT : tc;
                const int slot0 = (p & 1) * NT;
                for (int s = sbase; s < send; ++s) {
                    const float* zs = Z0 + (size_t)s * (NB * NH) + i0;
                    float4 zv[8];
                    #pragma unroll
                    for (int byt = 0; byt < 4; ++byt) {
                        zv[byt * 2]     = *reinterpret_cast<const float4*>(zs + byt * 128);
                        zv[byt * 2 + 1] = *reinterpret_cast<const float4*>(zs + byt * 128 + 4);
                    }
                    unsigned int bits = 0;
                    #pragma unroll
                    for (int e = 0; e < 32; ++e) {
                        float z = reinterpret_cast<const float*>(zv)[e];
                        float mn, sp;
                        leaky_upd(z, m0[e], be0[e], th0[e], mn, sp);
                        m0[e] = mn;
                        bits |= (sp != 0.0f ? 1u : 0u) << e;
                    }
                    ring0[(size_t)(slot0 + s - sbase) * BITFRAME + wi] = bits;
                }
            }
            gridbar(flags, gen, p + 1);
        }

        if (act) {
            #pragma unroll
            for (int byt = 0; byt < 4; ++byt)
                #pragma unroll
                for (int j = 0; j < 8; ++j)
                    mem0_g[i0 + byt * 128 + j] = m0[byt * 8 + j];
        }
    }
}

// ---------------- launch ----------------------------------------------------
extern "C" void kernel_launch(void* const* d_in, const int* in_sizes, int n_in,
                              void* d_out, int out_size, void* d_ws, size_t ws_size,
                              hipStream_t stream) {
    const float* data   = (const float*)d_in[0];
    const float* W_in   = (const float*)d_in[1];
    const float* b_in   = (const float*)d_in[2];
    const float* W_h    = (const float*)d_in[3];
    const float* b_h    = (const float*)d_in[4];
    const float* W_out  = (const float*)d_in[5];
    const float* b_out  = (const float*)d_in[6];
    const float* beta_h = (const float*)d_in[7];
    const float* thr_h  = (const float*)d_in[8];
    const float* beta_o = (const float*)d_in[9];
    const float* thr_o  = (const float*)d_in[10];
    float* out = (float*)d_out;

    char* ws = (char*)d_ws;
    float*        mem123 = (float*)(ws + WS_MEM123);
    float*        mem0_g = (float*)(ws + WS_MEM0);
    float*        memo_g = (float*)(ws + WS_MEMO);
    int*          flags  = (int*)(ws + WS_FLAGS);
    int*          gen    = (int*)(ws + WS_GEN);
    unsigned int* ring0  = (unsigned int*)(ws + WS_RING0);
    unsigned int* ring1  = (unsigned int*)(ws + WS_RING1);
    unsigned int* ring2  = (unsigned int*)(ws + WS_RING2);
    unsigned int* ring3  = (unsigned int*)(ws + WS_RING3);
    signed char*  W8     = (signed char*)(ws + WS_W8);
    __bf16*       Wi_t   = (__bf16*)(ws + WS_WIT);
    __bf16*       Wo_t   = (__bf16*)(ws + WS_WOT);
    float*        Z0     = (float*)(ws + WS_Z0);

    size_t avail = (ws_size > WS_Z0) ? (ws_size - WS_Z0) / STEP_BYTES : 1;
    int Tc = (int)(avail < 1 ? 1 : (avail > TT ? TT : avail));

    hipMemsetAsync(ws, 0, WS_RING0, stream);   // mem123+mem0+memo+flags+gen
    split_weights_i8<<<dim3(768), dim3(256), 0, stream>>>(W_h, W8);
    split_win<<<dim3(256), dim3(256), 0, stream>>>(W_in, Wi_t);
    split_wout<<<dim3(24), dim3(256), 0, stream>>>(W_out, Wo_t);

    for (int t0c = 0; t0c < TT; t0c += Tc) {
        const int tcc = (TT - t0c < Tc) ? (TT - t0c) : Tc;
        z0_gemm<<<dim3(NH / 128, tcc * (NB / 64)), dim3(256), 0, stream>>>(
            data + (size_t)t0c * NB * NI, Wi_t, b_in, Z0);
        hipMemsetAsync(ws + WS_FLAGS, 0, 1280, stream);   // flags + gen
        snn_pipe<<<dim3(256), dim3(1024), 0, stream>>>(
            Z0, W8, Wo_t, b_h, b_out, beta_h, thr_h, beta_o, thr_o,
            mem123, mem0_g, memo_g, ring0, ring1, ring2, ring3, out,
            flags, gen, t0c, tcc);
    }
}

// Round 20
// 1493.500 us; speedup vs baseline: 1.8784x; 1.8784x over previous
//
#include <hip/hip_runtime.h>
#include <hip/hip_bf16.h>

// SNN, 5 layers, T=100, B=512.  R20 = R17 (best verified: 1.4956 ms).
// i8 4-plane hidden path (exact i32 accum), bit-packed spikes, 5-stage
// 256-block persistent pipeline (hidden 0..191 | out 192..223 | leaky0
// 224..255), ck-desync per wave group + s_setprio around MFMA cluster,
// wide-tile z0_gemm prelude. absmax 0.0 verified.

#define NB 512
#define NH 1024
#define NI 512
#define NO 35
#define TT 100
#define NT 8
#define BITFRAME 16384   // u32 words per 512x1024 bit frame (64KB)

typedef __bf16 bf16x8 __attribute__((ext_vector_type(8)));
typedef float f32x4 __attribute__((ext_vector_type(4)));
typedef int   i32x4 __attribute__((ext_vector_type(4)));

__device__ __forceinline__ size_t tiled_off(int row, int k, int KT) {
    return ((size_t)((row >> 4) * KT + (k >> 5)) * 64
            + (row & 15) + (((k >> 3) & 3) << 4)) * 8 + (k & 7);
}

__device__ __forceinline__ void leaky_upd(float zin, float mprev, float be, float th,
                                          float& mnew, float& spk) {
    float rs = (mprev - th > 0.0f) ? th : 0.0f;
    float bc = fminf(fmaxf(be, 0.0f), 1.0f);
    mnew = bc * mprev + zin - rs;
    spk  = (mnew - th > 0.0f) ? 1.0f : 0.0f;
}

// ---------------- ws layout (bytes) ----------------
#define WS_MEM123   0u           // 6,291,456
#define WS_MEM0     6291456u     // 2,097,152 (tiled-linear fp32)
#define WS_MEMO     8388608u     // 98,304
#define WS_FLAGS    8486912u     // 1,024
#define WS_GEN      8487936u     // 256
#define WS_RING0    8488192u     // 16 frames = 1,048,576 each
#define WS_RING1    9536768u
#define WS_RING2    10585344u
#define WS_RING3    11633920u
#define WS_W8       12682496u    // 12,582,912 (3 layers x 4 planes x 1MB i8)
#define WS_WIT      25265408u    // 3,145,728 (W_in bf16 3 planes, KT=16)
#define WS_WOT      28411136u    // 294,912   (W_out bf16, 48 rows, 3 planes)
#define WS_Z0       28706048u    // Tc * 2,097,152
#define STEP_BYTES  2097152u

// ---------------- weight splits ----------------
__global__ __launch_bounds__(256)
void split_weights_i8(const float* __restrict__ W_h, signed char* __restrict__ W8) {
    const int id = blockIdx.x * 256 + threadIdx.x;        // 3*1024*64
    const int layer = id >> 16;
    const int rem = id & 65535;
    const int n = rem >> 6;
    const int k0 = (rem & 63) << 4;                        // 16 k per thread
    const float* src = W_h + ((size_t)layer * NH + n) * NH + k0;
    const int kq = k0 >> 4;
    const int ck = kq >> 2;
    const int lane = (n & 15) | ((kq & 3) << 4);
    signed char* dstL = W8 + (size_t)layer * 4 * NH * NH;
    const size_t gb = ((size_t)(n >> 4) * 16 + ck) * 1024 + lane * 16;

    signed char q1[16], q2[16], q3[16], q4[16];
    #pragma unroll
    for (int j = 0; j < 16; ++j) {
        float w = src[j];
        float f1 = rintf(w * 0x1p11f);   float r1 = w  - f1 * 0x1p-11f;
        float f2 = rintf(r1 * 0x1p18f);  float r2 = r1 - f2 * 0x1p-18f;
        float f3 = rintf(r2 * 0x1p25f);  float r3 = r2 - f3 * 0x1p-25f;
        float f4 = rintf(r3 * 0x1p32f);
        q1[j] = (signed char)(int)f1; q2[j] = (signed char)(int)f2;
        q3[j] = (signed char)(int)f3; q4[j] = (signed char)(int)f4;
    }
    #pragma unroll
    for (int j = 0; j < 16; ++j) {
        dstL[(size_t)0 * 64 * 16384 + gb + j] = q1[j];
        dstL[(size_t)1 * 64 * 16384 + gb + j] = q2[j];
        dstL[(size_t)2 * 64 * 16384 + gb + j] = q3[j];
        dstL[(size_t)3 * 64 * 16384 + gb + j] = q4[j];
    }
}

__global__ __launch_bounds__(256)
void split_win(const float* __restrict__ W_in, __bf16* __restrict__ Wi_t) {
    const int id = blockIdx.x * 256 + threadIdx.x;
    const int n = id >> 6;
    const int k0 = (id & 63) << 3;
    const float* src = W_in + (size_t)n * NI + k0;
    const size_t PS = (size_t)NH * NI;
    const size_t off = tiled_off(n, k0, 16);
    bf16x8 p1, p2, p3;
    #pragma unroll
    for (int j = 0; j < 8; ++j) {
        float w = src[j];
        __bf16 a = (__bf16)w;  float r1 = w - (float)a;
        __bf16 b = (__bf16)r1; float r2 = r1 - (float)b;
        __bf16 c = (__bf16)r2;
        p1[j] = a; p2[j] = b; p3[j] = c;
    }
    *reinterpret_cast<bf16x8*>(Wi_t + 0 * PS + off) = p1;
    *reinterpret_cast<bf16x8*>(Wi_t + 1 * PS + off) = p2;
    *reinterpret_cast<bf16x8*>(Wi_t + 2 * PS + off) = p3;
}

__global__ __launch_bounds__(256)
void split_wout(const float* __restrict__ W_out, __bf16* __restrict__ Wo_t) {
    const int id = blockIdx.x * 256 + threadIdx.x;
    if (id >= 48 * 128) return;
    const int o = id >> 7;
    const int k0 = (id & 127) << 3;
    const size_t PS = (size_t)48 * NH;
    const size_t off = tiled_off(o, k0, 32);
    bf16x8 p1 = {}, p2 = {}, p3 = {};
    if (o < NO) {
        const float* src = W_out + (size_t)o * NH + k0;
        #pragma unroll
        for (int j = 0; j < 8; ++j) {
            float w = src[j];
            __bf16 a = (__bf16)w;  float r1 = w - (float)a;
            __bf16 b = (__bf16)r1; float r2 = r1 - (float)b;
            __bf16 c = (__bf16)r2;
            p1[j] = a; p2[j] = b; p3[j] = c;
        }
    }
    *reinterpret_cast<bf16x8*>(Wo_t + 0 * PS + off) = p1;
    *reinterpret_cast<bf16x8*>(Wo_t + 1 * PS + off) = p2;
    *reinterpret_cast<bf16x8*>(Wo_t + 2 * PS + off) = p3;
}

// ---------------- Z0 = data @ W_in^T + b_in ---------------------------------
// Block 64m x 128n, 4 waves 2x2; wave tile 32m x 64n (nt=0..3).
__global__ __launch_bounds__(256)
void z0_gemm(const float* __restrict__ X,
             const __bf16* __restrict__ Wi_t,
             const float* __restrict__ bias,
             float* __restrict__ Z0)
{
    const int tid = threadIdx.x;
    const int lane = tid & 63;
    const int w = tid >> 6;
    const int wm = w >> 1, wn = w & 1;
    const int m_base = blockIdx.y * 64 + wm * 32;
    const int n_base = blockIdx.x * 128 + wn * 64;
    const size_t PS = (size_t)NH * NI;

    f32x4 acc[2][4] = {};
    const float* asrc[2];
    #pragma unroll
    for (int mt = 0; mt < 2; ++mt)
        asrc[mt] = X + (size_t)(m_base + mt * 16 + (lane & 15)) * NI + ((lane >> 4) << 3);

    float4 c0[2], c1[2];
    #pragma unroll
    for (int mt = 0; mt < 2; ++mt) {
        c0[mt] = *reinterpret_cast<const float4*>(asrc[mt]);
        c1[mt] = *reinterpret_cast<const float4*>(asrc[mt] + 4);
    }

    for (int kt = 0; kt < 16; ++kt) {
        float4 n0[2], n1[2];
        if (kt < 15) {
            #pragma unroll
            for (int mt = 0; mt < 2; ++mt) {
                n0[mt] = *reinterpret_cast<const float4*>(asrc[mt] + (kt + 1) * 32);
                n1[mt] = *reinterpret_cast<const float4*>(asrc[mt] + (kt + 1) * 32 + 4);
            }
        }
        bf16x8 a1[2], a2[2], a3[2];
        #pragma unroll
        for (int mt = 0; mt < 2; ++mt) {
            float xv[8] = {c0[mt].x, c0[mt].y, c0[mt].z, c0[mt].w,
                           c1[mt].x, c1[mt].y, c1[mt].z, c1[mt].w};
            #pragma unroll
            for (int j = 0; j < 8; ++j) {
                float x = xv[j];
                __bf16 h1 = (__bf16)x;  float r1 = x - (float)h1;
                __bf16 h2 = (__bf16)r1; float r2 = r1 - (float)h2;
                __bf16 h3 = (__bf16)r2;
                a1[mt][j] = h1; a2[mt][j] = h2; a3[mt][j] = h3;
            }
        }
        #pragma unroll
        for (int nt = 0; nt < 4; ++nt) {
            const size_t bo = ((size_t)(((n_base >> 4) + nt) * 16 + kt) * 64 + lane) * 8;
            bf16x8 b1 = *reinterpret_cast<const bf16x8*>(Wi_t + bo);
            bf16x8 b2 = *reinterpret_cast<const bf16x8*>(Wi_t + PS + bo);
            bf16x8 b3 = *reinterpret_cast<const bf16x8*>(Wi_t + 2 * PS + bo);
            #pragma unroll
            for (int mt = 0; mt < 2; ++mt) {
                f32x4 A = acc[mt][nt];
                A = __builtin_amdgcn_mfma_f32_16x16x32_bf16(a1[mt], b1, A, 0, 0, 0);
                A = __builtin_amdgcn_mfma_f32_16x16x32_bf16(a1[mt], b2, A, 0, 0, 0);
                A = __builtin_amdgcn_mfma_f32_16x16x32_bf16(a2[mt], b1, A, 0, 0, 0);
                A = __builtin_amdgcn_mfma_f32_16x16x32_bf16(a2[mt], b2, A, 0, 0, 0);
                A = __builtin_amdgcn_mfma_f32_16x16x32_bf16(a1[mt], b3, A, 0, 0, 0);
                A = __builtin_amdgcn_mfma_f32_16x16x32_bf16(a3[mt], b1, A, 0, 0, 0);
                acc[mt][nt] = A;
            }
        }
        if (kt < 15) {
            #pragma unroll
            for (int mt = 0; mt < 2; ++mt) { c0[mt] = n0[mt]; c1[mt] = n1[mt]; }
        }
    }

    const int c = lane & 15;
    const int r0 = (lane >> 4) * 4;
    #pragma unroll
    for (int nt = 0; nt < 4; ++nt) {
        const int n = n_base + nt * 16 + c;
        const float bi = bias[n];
        #pragma unroll
        for (int mt = 0; mt < 2; ++mt) {
            #pragma unroll
            for (int r = 0; r < 4; ++r) {
                const int m = m_base + mt * 16 + r0 + r;
                const int tl = m >> 9, b = m & 511;
                Z0[(size_t)tl * (NB * NH) + tiled_off(b, n, 32)] = acc[mt][nt][r] + bi;
            }
        }
    }
}

// ---------------- grid barrier (256 blocks) ----------------------------------
__device__ __forceinline__ void gridbar(int* flags, int* gen, int target) {
    __syncthreads();
    if (threadIdx.x == 0) {
        __builtin_amdgcn_fence(__ATOMIC_RELEASE, "agent");
        __hip_atomic_store(&flags[blockIdx.x], target, __ATOMIC_RELAXED, __HIP_MEMORY_SCOPE_AGENT);
    }
    if (blockIdx.x == 0) {
        if (threadIdx.x < 64) {
            const int l = threadIdx.x;
            for (;;) {
                int v0 = __hip_atomic_load(&flags[l],       __ATOMIC_RELAXED, __HIP_MEMORY_SCOPE_AGENT);
                int v1 = __hip_atomic_load(&flags[l + 64],  __ATOMIC_RELAXED, __HIP_MEMORY_SCOPE_AGENT);
                int v2 = __hip_atomic_load(&flags[l + 128], __ATOMIC_RELAXED, __HIP_MEMORY_SCOPE_AGENT);
                int v3 = __hip_atomic_load(&flags[l + 192], __ATOMIC_RELAXED, __HIP_MEMORY_SCOPE_AGENT);
                int mn = min(min(v0, v1), min(v2, v3));
                if (__all(mn >= target)) break;
                __builtin_amdgcn_s_sleep(1);
            }
        }
        __syncthreads();
        if (threadIdx.x == 0) {
            __builtin_amdgcn_fence(__ATOMIC_ACQ_REL, "agent");
            __hip_atomic_store(gen, target, __ATOMIC_RELAXED, __HIP_MEMORY_SCOPE_AGENT);
        }
    } else if (threadIdx.x == 0) {
        while (__hip_atomic_load(gen, __ATOMIC_RELAXED, __HIP_MEMORY_SCOPE_AGENT) < target)
            __builtin_amdgcn_s_sleep(2);
    }
    __syncthreads();
    __builtin_amdgcn_fence(__ATOMIC_ACQUIRE, "agent");
}

// ---------------- hidden NS-step body (i8 4-plane, desynced ck loop) ---------
template<int NS>
__device__ __forceinline__ void hidden_run_i8(
    const unsigned int* const* Xp, unsigned short* const* Yp,
    const signed char* Wl, int cs, int rh, int w, int lane, int ckoff,
    float (&memr)[2][2][4], const float (&bi)[2], const float (&be)[2],
    const float (&th)[2])
{
    const int row  = lane & 15;
    const int lg   = lane >> 4;
    const int wsel = lg >> 1;          // word within chunk (2 per chunk)
    const int hsel = (lg & 1) * 16;    // halfword shift

    i32x4 acc[NS][2][2][4] = {};       // [q][i][nt][plane]

    unsigned int bw[NS][2];
    #pragma unroll
    for (int q = 0; q < NS; ++q)
        #pragma unroll
        for (int i = 0; i < 2; ++i)
            bw[q][i] = Xp[q][((rh * 16 + w * 2 + i) * 32 + ckoff * 2 + wsel) * 16 + row];

    i32x4 bf[8];
    #pragma unroll
    for (int pn = 0; pn < 8; ++pn)
        bf[pn] = *reinterpret_cast<const i32x4*>(Wl + pn * 16384 + ckoff * 1024 + lane * 16);

    for (int ckk = 0; ckk < 16; ++ckk) {
        const int ck = (ckk + ckoff) & 15;
        const int ckn = (ck + 1) & 15;
        unsigned int nb[NS][2];
        i32x4 nf[8];
        if (ckk < 15) {
            #pragma unroll
            for (int pn = 0; pn < 8; ++pn)
                nf[pn] = *reinterpret_cast<const i32x4*>(
                    Wl + pn * 16384 + ckn * 1024 + lane * 16);
            #pragma unroll
            for (int q = 0; q < NS; ++q)
                #pragma unroll
                for (int i = 0; i < 2; ++i)
                    nb[q][i] = Xp[q][((rh * 16 + w * 2 + i) * 32 + ckn * 2 + wsel) * 16 + row];
        }

        __builtin_amdgcn_s_setprio(1);
        #pragma unroll
        for (int q = 0; q < NS; ++q) {
            #pragma unroll
            for (int i = 0; i < 2; ++i) {
                unsigned int half = (bw[q][i] >> hsel) & 0xFFFFu;
                union { unsigned int u[4]; i32x4 v; } a;
                a.u[0] = (((half      ) & 0xFu) * 0x204081u) & 0x01010101u;
                a.u[1] = (((half >>  4) & 0xFu) * 0x204081u) & 0x01010101u;
                a.u[2] = (((half >>  8) & 0xFu) * 0x204081u) & 0x01010101u;
                a.u[3] = (((half >> 12) & 0xFu) * 0x204081u) & 0x01010101u;
                #pragma unroll
                for (int nt = 0; nt < 2; ++nt)
                    #pragma unroll
                    for (int p = 0; p < 4; ++p)
                        acc[q][i][nt][p] = __builtin_amdgcn_mfma_i32_16x16x64_i8(
                            a.v, bf[p * 2 + nt], acc[q][i][nt][p], 0, 0, 0);
            }
        }
        __builtin_amdgcn_s_setprio(0);

        if (ckk < 15) {
            #pragma unroll
            for (int q = 0; q < NS; ++q) { bw[q][0] = nb[q][0]; bw[q][1] = nb[q][1]; }
            #pragma unroll
            for (int pn = 0; pn < 8; ++pn) bf[pn] = nf[pn];
        }
    }

    #pragma unroll
    for (int q = 0; q < NS; ++q) {
        #pragma unroll
        for (int i = 0; i < 2; ++i) {
            #pragma unroll
            for (int nt = 0; nt < 2; ++nt) {
                #pragma unroll
                for (int r = 0; r < 4; ++r) {
                    float z = (float)acc[q][i][nt][3][r] * 0x1p-32f
                            + (float)acc[q][i][nt][2][r] * 0x1p-25f;
                    z += (float)acc[q][i][nt][1][r] * 0x1p-18f;
                    z += (float)acc[q][i][nt][0][r] * 0x1p-11f;
                    float mn, sp;
                    leaky_upd(z + bi[nt], memr[i][nt][r], be[nt], th[nt], mn, sp);
                    memr[i][nt][r] = mn;
                    unsigned long long bal = __ballot(sp != 0.0f);
                    if ((lane & 15) == 0) {
                        const int rr = (lane >> 4) * 4 + r;
                        Yp[q][(((rh * 16 + w * 2 + i) * 32 + cs) * 16 + rr) * 2 + nt] =
                            (unsigned short)((bal >> ((lane >> 4) * 16)) & 0xFFFFu);
                    }
                }
            }
        }
    }
}

// ---------------- the 5-stage persistent pipeline ----------------------------
__global__ __launch_bounds__(512, 1)
void snn_pipe(const float* __restrict__ Z0,
              const signed char* __restrict__ W8,
              const __bf16* __restrict__ Wo_t,
              const float* __restrict__ b_h,
              const float* __restrict__ b_out,
              const float* __restrict__ beta_h,
              const float* __restrict__ thr_h,
              const float* __restrict__ beta_o,
              const float* __restrict__ thr_o,
              float* __restrict__ mem123,
              float* __restrict__ mem0_g,
              float* __restrict__ memo_g,
              unsigned int* __restrict__ ring0, unsigned int* __restrict__ ring1,
              unsigned int* __restrict__ ring2, unsigned int* __restrict__ ring3,
              float* __restrict__ out,
              int* __restrict__ flags, int* __restrict__ gen,
              int t0, int tc)
{
    __shared__ signed char Wl[8 * 16 * 1024];    // 128 KB i8 weights
    __shared__ unsigned long long lut[16];       // for out stage

    const int blk  = blockIdx.x;
    const int tid  = threadIdx.x;
    const int lane = tid & 63;
    const int w    = tid >> 6;

    if (tid < 16) {
        unsigned int lo = ((tid & 1) ? 0x3F80u : 0u) | ((tid & 2) ? 0x3F800000u : 0u);
        unsigned int hi = ((tid & 4) ? 0x3F80u : 0u) | ((tid & 8) ? 0x3F800000u : 0u);
        lut[tid] = ((unsigned long long)hi << 32) | lo;
    }

    const int G = (tc + NT - 1) / NT;

    if (blk < 192) {
        // ================= hidden layers (i8) =================
        const int ell = blk >> 6;
        const int cs  = (blk & 63) >> 1;
        const int rh  = blk & 1;
        const int ckoff = (w >> 2) * 8;   // SIMD-mates (w, w+4) get opposite halves
        {
            const signed char* Wsrc = W8 + (size_t)ell * 4 * NH * NH;
            for (int idx = tid; idx < 8 * 1024; idx += 512) {
                const int pn = idx >> 10, off = idx & 1023;
                const int p = pn >> 1, nt = pn & 1;
                *reinterpret_cast<int4*>(Wl + pn * 16384 + off * 16) =
                    *reinterpret_cast<const int4*>(
                        Wsrc + (size_t)(p * 64 + cs * 2 + nt) * 16384 + off * 16);
            }
        }

        const int c = lane & 15;
        const int r0v = (lane >> 4) * 4;
        float* memg = mem123 + (size_t)ell * (NB * NH);
        float bi[2], be[2], th[2];
        #pragma unroll
        for (int nt = 0; nt < 2; ++nt) {
            const int n = cs * 32 + nt * 16 + c;
            bi[nt] = b_h[ell * NH + n];
            be[nt] = beta_h[(ell + 1) * NH + n];
            th[nt] = thr_h[(ell + 1) * NH + n];
        }
        float memr[2][2][4];
        #pragma unroll
        for (int i = 0; i < 2; ++i)
            #pragma unroll
            for (int nt = 0; nt < 2; ++nt)
                #pragma unroll
                for (int r = 0; r < 4; ++r)
                    memr[i][nt][r] = memg[(size_t)(rh * 256 + (w * 2 + i) * 16 + r0v + r) * NH
                                          + cs * 32 + nt * 16 + c];

        const unsigned int* rin = (ell == 0) ? ring0 : (ell == 1) ? ring1 : ring2;
        unsigned int* rout      = (ell == 0) ? ring1 : (ell == 1) ? ring2 : ring3;

        __syncthreads();

        for (int p = 0; p < G + 4; ++p) {
            const int g = p - 1 - ell;
            if (g >= 0 && g < G) {
                const int sbase = g * NT;
                const int send  = (sbase + NT < tc) ? sbase + NT : tc;
                const int slot0 = (g & 1) * NT;
                int s = sbase;
                while (s < send) {
                    const int base = slot0 + (s - sbase);
                    const unsigned int* Xp[2];
                    unsigned short* Yp[2];
                    if (send - s >= 2) {
                        #pragma unroll
                        for (int q = 0; q < 2; ++q) {
                            Xp[q] = rin + (size_t)(base + q) * BITFRAME;
                            Yp[q] = (unsigned short*)(rout + (size_t)(base + q) * BITFRAME);
                        }
                        hidden_run_i8<2>(Xp, Yp, Wl, cs, rh, w, lane, ckoff, memr, bi, be, th);
                        s += 2;
                    } else {
                        Xp[0] = rin + (size_t)base * BITFRAME;
                        Yp[0] = (unsigned short*)(rout + (size_t)base * BITFRAME);
                        hidden_run_i8<1>(Xp, Yp, Wl, cs, rh, w, lane, ckoff, memr, bi, be, th);
                        s += 1;
                    }
                }
            }
            gridbar(flags, gen, p + 1);
        }

        #pragma unroll
        for (int i = 0; i < 2; ++i)
            #pragma unroll
            for (int nt = 0; nt < 2; ++nt)
                #pragma unroll
                for (int r = 0; r < 4; ++r)
                    memg[(size_t)(rh * 256 + (w * 2 + i) * 16 + r0v + r) * NH
                         + cs * 32 + nt * 16 + c] = memr[i][nt][r];
    } else if (blk < 224) {
        // ================= output layer (bf16 LUT) =================
        const bool outw = (w < 3);
        const int omt = blk - 192;
        const int ont = w;
        const int c = lane & 15, r0v = (lane >> 4) * 4;
        const int row = lane & 15, sh2 = (lane >> 4) * 8;
        const int oo = ont * 16 + c;
        const size_t OPS = (size_t)48 * NH;
        float mo[4] = {0.f, 0.f, 0.f, 0.f};
        float obi = 0.f, obe = 0.f, oth = 1.f;
        if (outw && oo < NO) {
            obi = b_out[oo]; obe = beta_o[oo]; oth = thr_o[oo];
            #pragma unroll
            for (int r = 0; r < 4; ++r) mo[r] = memo_g[(omt * 16 + r0v + r) * NO + oo];
        }
        __syncthreads();

        for (int p = 0; p < G + 4; ++p) {
            if (outw) {
                const int go = p - 4;
                if (go >= 0 && go < G) {
                    const int sbase = go * NT;
                    const int send  = (sbase + NT < tc) ? sbase + NT : tc;
                    const int slot0 = (go & 1) * NT;
                    for (int s = sbase; s < send; ++s) {
                        const unsigned int* Xw =
                            ring3 + (size_t)(slot0 + s - sbase) * BITFRAME;
                        f32x4 acc = {};
                        for (int kt = 0; kt < 32; ++kt) {
                            unsigned int by = (Xw[(omt * 32 + kt) * 16 + row] >> sh2) & 0xffu;
                            union { unsigned long long u[2]; bf16x8 v; } a;
                            a.u[0] = lut[by & 15u];
                            a.u[1] = lut[by >> 4];
                            const size_t bo = ((size_t)(ont * 32 + kt) * 64 + lane) * 8;
                            bf16x8 q1 = *reinterpret_cast<const bf16x8*>(Wo_t + bo);
                            bf16x8 q2 = *reinterpret_cast<const bf16x8*>(Wo_t + OPS + bo);
                            bf16x8 q3 = *reinterpret_cast<const bf16x8*>(Wo_t + 2 * OPS + bo);
                            acc = __builtin_amdgcn_mfma_f32_16x16x32_bf16(a.v, q1, acc, 0, 0, 0);
                            acc = __builtin_amdgcn_mfma_f32_16x16x32_bf16(a.v, q2, acc, 0, 0, 0);
                            acc = __builtin_amdgcn_mfma_f32_16x16x32_bf16(a.v, q3, acc, 0, 0, 0);
                        }
                        if (oo < NO) {
                            #pragma unroll
                            for (int r = 0; r < 4; ++r) {
                                float mn, sp;
                                leaky_upd(acc[r] + obi, mo[r], obe, oth, mn, sp);
                                mo[r] = mn;
                                out[((size_t)(t0 + s) * NB + omt * 16 + r0v + r) * NO + oo] = sp;
                            }
                        }
                    }
                }
            }
            gridbar(flags, gen, p + 1);
        }

        if (outw && oo < NO) {
            #pragma unroll
            for (int r = 0; r < 4; ++r) memo_g[(omt * 16 + r0v + r) * NO + oo] = mo[r];
        }
    } else {
        // ================= leaky0: one u32 bit-word (32 elems) per thread ====
        const int wi   = (blk - 224) * 512 + tid;     // 0..16383
        const int mtb  = wi >> 9;
        const int ktb  = (wi >> 4) & 31;
        const int i0   = (mtb * 32 + ktb) * 512 + (wi & 15) * 8;

        float m0[32], be0[32], th0[32];
        #pragma unroll
        for (int byt = 0; byt < 4; ++byt)
            #pragma unroll
            for (int j = 0; j < 8; ++j) {
                m0[byt * 8 + j]  = mem0_g[i0 + byt * 128 + j];
                be0[byt * 8 + j] = beta_h[ktb * 32 + byt * 8 + j];
                th0[byt * 8 + j] = thr_h[ktb * 32 + byt * 8 + j];
            }
        __syncthreads();

        for (int p = 0; p < G + 4; ++p) {
            if (p < G) {
                const int sbase = p * NT;
                const int send  = (sbase + NT < tc) ? sbase + NT : tc;
                const int slot0 = (p & 1) * NT;
                for (int s = sbase; s < send; ++s) {
                    const float* zs = Z0 + (size_t)s * (NB * NH) + i0;
                    float4 zv[8];
                    #pragma unroll
                    for (int byt = 0; byt < 4; ++byt) {
                        zv[byt * 2]     = *reinterpret_cast<const float4*>(zs + byt * 128);
                        zv[byt * 2 + 1] = *reinterpret_cast<const float4*>(zs + byt * 128 + 4);
                    }
                    unsigned int bits = 0;
                    #pragma unroll
                    for (int e = 0; e < 32; ++e) {
                        float z = reinterpret_cast<const float*>(zv)[e];
                        float mn, sp;
                        leaky_upd(z, m0[e], be0[e], th0[e], mn, sp);
                        m0[e] = mn;
                        bits |= (sp != 0.0f ? 1u : 0u) << e;
                    }
                    ring0[(size_t)(slot0 + s - sbase) * BITFRAME + wi] = bits;
                }
            }
            gridbar(flags, gen, p + 1);
        }

        #pragma unroll
        for (int byt = 0; byt < 4; ++byt)
            #pragma unroll
            for (int j = 0; j < 8; ++j)
                mem0_g[i0 + byt * 128 + j] = m0[byt * 8 + j];
    }
}

// ---------------- launch ----------------------------------------------------
extern "C" void kernel_launch(void* const* d_in, const int* in_sizes, int n_in,
                              void* d_out, int out_size, void* d_ws, size_t ws_size,
                              hipStream_t stream) {
    const float* data   = (const float*)d_in[0];
    const float* W_in   = (const float*)d_in[1];
    const float* b_in   = (const float*)d_in[2];
    const float* W_h    = (const float*)d_in[3];
    const float* b_h    = (const float*)d_in[4];
    const float* W_out  = (const float*)d_in[5];
    const float* b_out  = (const float*)d_in[6];
    const float* beta_h = (const float*)d_in[7];
    const float* thr_h  = (const float*)d_in[8];
    const float* beta_o = (const float*)d_in[9];
    const float* thr_o  = (const float*)d_in[10];
    float* out = (float*)d_out;

    char* ws = (char*)d_ws;
    float*        mem123 = (float*)(ws + WS_MEM123);
    float*        mem0_g = (float*)(ws + WS_MEM0);
    float*        memo_g = (float*)(ws + WS_MEMO);
    int*          flags  = (int*)(ws + WS_FLAGS);
    int*          gen    = (int*)(ws + WS_GEN);
    unsigned int* ring0  = (unsigned int*)(ws + WS_RING0);
    unsigned int* ring1  = (unsigned int*)(ws + WS_RING1);
    unsigned int* ring2  = (unsigned int*)(ws + WS_RING2);
    unsigned int* ring3  = (unsigned int*)(ws + WS_RING3);
    signed char*  W8     = (signed char*)(ws + WS_W8);
    __bf16*       Wi_t   = (__bf16*)(ws + WS_WIT);
    __bf16*       Wo_t   = (__bf16*)(ws + WS_WOT);
    float*        Z0     = (float*)(ws + WS_Z0);

    size_t avail = (ws_size > WS_Z0) ? (ws_size - WS_Z0) / STEP_BYTES : 1;
    int Tc = (int)(avail < 1 ? 1 : (avail > TT ? TT : avail));

    hipMemsetAsync(ws, 0, WS_RING0, stream);   // mem123+mem0+memo+flags+gen
    split_weights_i8<<<dim3(768), dim3(256), 0, stream>>>(W_h, W8);
    split_win<<<dim3(256), dim3(256), 0, stream>>>(W_in, Wi_t);
    split_wout<<<dim3(24), dim3(256), 0, stream>>>(W_out, Wo_t);

    for (int t0c = 0; t0c < TT; t0c += Tc) {
        const int tcc = (TT - t0c < Tc) ? (TT - t0c) : Tc;
        z0_gemm<<<dim3(NH / 128, tcc * (NB / 64)), dim3(256), 0, stream>>>(
            data + (size_t)t0c * NB * NI, Wi_t, b_in, Z0);
        hipMemsetAsync(ws + WS_FLAGS, 0, 1280, stream);   // flags + gen
        snn_pipe<<<dim3(256), dim3(512), 0, stream>>>(
            Z0, W8, Wo_t, b_h, b_out, beta_h, thr_h, beta_o, thr_o,
            mem123, mem0_g, memo_g, ring0, ring1, ring2, ring3, out,
            flags, gen, t0c, tcc);
    }
}